// Round 11
// baseline (87.391 us; speedup 1.0000x reference)
//
#include <hip/hip_runtime.h>

// Problem constants (match reference)
#define B_ 16
#define F_ 256
#define N_ 16384
#define L_ 4096
#define K_ 9

#define NTHR 1024
#define NBLK 256                       // 1 block/CU (128.3 KiB LDS)
#define ROWS_PER_BLK (B_ * F_ / NBLK)  // 16

typedef const __attribute__((address_space(1))) void* gas_ptr;
typedef __attribute__((address_space(3))) void* las_ptr;

// ---------------------------------------------------------------------------
// Fully fused double-buffered DMA pipeline (single dispatch).
//
//  prologue: issue the 72 one-time idx/mask loads, THEN DMA(row0) — in-order
//            vmcnt retire means building cpk waits only for the loads, with
//            the row-0 DMA still in flight; one full-drain __syncthreads.
//  round p:  issue DMA(p+1) -> compute p (pure ds_read/fmax/store; cpk is
//            row-invariant so no global loads, no vmcnt waits) ->
//            s_waitcnt vmcnt(4) + raw s_barrier: DMA(p+1) is retired (it is
//            older than the 4 output stores), stores stay in flight (T4 —
//            never drain to 0 in the steady loop).
// ---------------------------------------------------------------------------
__global__ __launch_bounds__(NTHR) void pool_fused_kernel(
    const float* __restrict__ img, const int* __restrict__ idx,
    const float* __restrict__ mask, float* __restrict__ out) {
  __shared__ __align__(16) float buf[2][N_ + 16];  // sentinel at [s][N_]
  const int tid = threadIdx.x;
  const int bid = blockIdx.x;
  const int lane = tid & 63;
  const int wv = tid >> 6;  // 0..15

  // Stage helper: 64 KiB = 64 chunks of 1 KiB (64 lanes x 16 B); wave w owns
  // chunks w, w+16, w+32, w+48. LDS dest is wave-uniform base + lane*16 (HW).
#define STAGE_ROW(row_, dstbuf_)                                              \
  {                                                                           \
    const float* src_ = img + (size_t)(row_)*N_;                              \
    _Pragma("unroll") for (int i_ = 0; i_ < 4; ++i_) {                        \
      const int c_ = i_ * 16 + wv;                                            \
      __builtin_amdgcn_global_load_lds((gas_ptr)(src_ + c_ * 256 + lane * 4), \
                                       (las_ptr)((dstbuf_) + c_ * 256),       \
                                       16, 0, 0);                             \
    }                                                                         \
  }

  // ---- build this thread's 36 row-invariant indices into 18 packed VGPRs
  //      (loads issued before the DMA; masked entry -> sentinel N_) ----
  unsigned cpk[18];
#pragma unroll
  for (int j = 0; j < 18; ++j) {
    const int s0 = 2 * j, s1 = 2 * j + 1;  // flat slots it*K_+k
    const int t0 = (s0 / K_ * NTHR + tid) * K_ + s0 % K_;
    const int t1 = (s1 / K_ * NTHR + tid) * K_ + s1 % K_;
    unsigned a = (mask[t0] != 0.0f) ? (unsigned)idx[t0] : (unsigned)N_;
    unsigned b = (mask[t1] != 0.0f) ? (unsigned)idx[t1] : (unsigned)N_;
    cpk[j] = a | (b << 16);
  }

  // ---- prologue: stage row 0, init sentinels, full drain ----
  STAGE_ROW(bid, &buf[0][0]);
  if (tid < 2) buf[tid][N_] = 0.0f;
  __syncthreads();  // drains row-0 DMA (and the cpk loads)

#pragma unroll 1
  for (int p = 0; p < ROWS_PER_BLK; ++p) {
    // 1. issue next row's DMA (per wave: 4 ops, no VGPRs held)
    if (p + 1 < ROWS_PER_BLK) {
      STAGE_ROW((p + 1) * NBLK + bid, &buf[(p + 1) & 1][0]);
    }

    // 2. gather row p — ds_read/fmax/store only; all cpk indexing static
    const float* row = &buf[p & 1][0];
    float* outp = out + (size_t)((size_t)p * NBLK + bid) * L_;
#pragma unroll
    for (int it = 0; it < L_ / NTHR; ++it) {  // 4 iters
      int l = it * NTHR + tid;
      float v[K_];
#pragma unroll
      for (int k = 0; k < K_; ++k) {
        const int slot = it * K_ + k;  // compile-time constant
        unsigned w = cpk[slot >> 1];
        unsigned id = (slot & 1) ? (w >> 16) : (w & 0xffffu);
        v[k] = row[id];  // ds_read (sentinel -> 0.0f)
      }
      float t0 = fmaxf(fmaxf(v[0], v[1]), v[2]);  // v_max3 tree
      float t1 = fmaxf(fmaxf(v[3], v[4]), v[5]);
      float t2 = fmaxf(fmaxf(v[6], v[7]), v[8]);
      outp[l] = fmaxf(fmaxf(t0, t1), t2);  // coalesced
    }

    // 3. counted-vmcnt barrier: per-wave issue order was
    //    [4x DMA(p+1)][4x store(p)] and vmcnt retires in order, so
    //    vmcnt(4) == "DMA(p+1) landed", with stores left in flight.
    if (p + 1 < ROWS_PER_BLK) {
      asm volatile("s_waitcnt vmcnt(4)" ::: "memory");
      __builtin_amdgcn_s_barrier();
    }
    // last round: end-of-kernel implicit drain covers the stores
  }
#undef STAGE_ROW
}

extern "C" void kernel_launch(void* const* d_in, const int* in_sizes, int n_in,
                              void* d_out, int out_size, void* d_ws, size_t ws_size,
                              hipStream_t stream) {
  const float* img = (const float*)d_in[0];
  const int* idx = (const int*)d_in[1];
  const float* mask = (const float*)d_in[2];
  float* out = (float*)d_out;
  pool_fused_kernel<<<NBLK, NTHR, 0, stream>>>(img, idx, mask, out);
}

// Round 12
// 72.171 us; speedup vs baseline: 1.2109x; 1.2109x over previous
//
#include <hip/hip_runtime.h>

// Problem constants (match reference)
#define B_ 16
#define F_ 256
#define N_ 16384
#define L_ 4096
#define K_ 9

#define NTHR 1024
#define NBLK 256                       // 1 block/CU (128.3 KiB LDS)
#define ROWS_PER_BLK (B_ * F_ / NBLK)  // 16

typedef const __attribute__((address_space(1))) void* gas_ptr;
typedef __attribute__((address_space(3))) void* las_ptr;

// ---------------------------------------------------------------------------
// Pre-pass: fold mask into index, transpose to (K, L) ushort.
// masked (mask==0) -> sentinel index N_ (LDS slot N_ holds 0.0f).
// Coalesced both ways; keeps the pool kernel's cpk preload coalesced too
// (R11 showed inlining this costs 14 us in stride-9 over-fetch).
// ---------------------------------------------------------------------------
__global__ __launch_bounds__(256) void prep_comb_kernel(
    const int* __restrict__ idx, const float* __restrict__ mask,
    unsigned short* __restrict__ comb) {
  int t = blockIdx.x * blockDim.x + threadIdx.x;  // over L_*K_
  if (t >= L_ * K_) return;
  int l = t / K_;
  int k = t - l * K_;
  comb[k * L_ + l] =
      (mask[t] != 0.0f) ? (unsigned short)idx[t] : (unsigned short)N_;
}

// ---------------------------------------------------------------------------
// R10 double-buffered DMA pipeline + T4 counted-vmcnt barrier.
//  round p: issue DMA(p+1) -> gather row p (pure ds_read/fmax/store, no
//  vmcnt waits: cpk indices live in VGPRs) -> s_waitcnt vmcnt(4) + raw
//  s_barrier (DMA(p+1) retired, the 4 output stores stay in flight).
// ---------------------------------------------------------------------------
__global__ __launch_bounds__(NTHR) void pool_pipe_kernel(
    const float* __restrict__ img, const unsigned short* __restrict__ comb,
    float* __restrict__ out) {
  __shared__ __align__(16) float buf[2][N_ + 16];  // sentinel at [s][N_]
  const int tid = threadIdx.x;
  const int bid = blockIdx.x;
  const int lane = tid & 63;
  const int wv = tid >> 6;  // 0..15

  // ---- preload this thread's 36 row-invariant indices into 18 VGPRs ----
  // slot s = it*K_+k  ->  comb[k*L_ + it*NTHR + tid]   (coalesced u16)
  unsigned cpk[18];
#pragma unroll
  for (int j = 0; j < 18; ++j) {
    const int s0 = 2 * j, s1 = 2 * j + 1;
    const int it0 = s0 / K_, k0 = s0 % K_;
    const int it1 = s1 / K_, k1 = s1 % K_;
    unsigned a = comb[k0 * L_ + it0 * NTHR + tid];
    unsigned b = comb[k1 * L_ + it1 * NTHR + tid];
    cpk[j] = a | (b << 16);
  }

  // Stage helper: 64 KiB = 64 chunks of 1 KiB (64 lanes x 16 B); wave w owns
  // chunks w, w+16, w+32, w+48. LDS dest is wave-uniform base + lane*16 (HW).
#define STAGE_ROW(row_, dstbuf_)                                              \
  {                                                                           \
    const float* src_ = img + (size_t)(row_)*N_;                              \
    _Pragma("unroll") for (int i_ = 0; i_ < 4; ++i_) {                        \
      const int c_ = i_ * 16 + wv;                                            \
      __builtin_amdgcn_global_load_lds((gas_ptr)(src_ + c_ * 256 + lane * 4), \
                                       (las_ptr)((dstbuf_) + c_ * 256),       \
                                       16, 0, 0);                             \
    }                                                                         \
  }

  // prologue: stage row 0, init both sentinels, full drain (once)
  STAGE_ROW(bid, &buf[0][0]);
  if (tid < 2) buf[tid][N_] = 0.0f;
  __syncthreads();

#pragma unroll 1
  for (int p = 0; p < ROWS_PER_BLK; ++p) {
    // 1. issue next row's DMA (4 ops/wave, no VGPRs held -> cannot sink)
    if (p + 1 < ROWS_PER_BLK) {
      STAGE_ROW((p + 1) * NBLK + bid, &buf[(p + 1) & 1][0]);
    }

    // 2. gather row p — ds_read/fmax/store only; all cpk indexing static
    const float* row = &buf[p & 1][0];
    float* outp = out + (size_t)((size_t)p * NBLK + bid) * L_;
#pragma unroll
    for (int it = 0; it < L_ / NTHR; ++it) {  // 4 iters
      int l = it * NTHR + tid;
      float v[K_];
#pragma unroll
      for (int k = 0; k < K_; ++k) {
        const int slot = it * K_ + k;  // compile-time constant
        unsigned w = cpk[slot >> 1];
        unsigned id = (slot & 1) ? (w >> 16) : (w & 0xffffu);
        v[k] = row[id];  // ds_read (sentinel -> 0.0f)
      }
      float t0 = fmaxf(fmaxf(v[0], v[1]), v[2]);  // v_max3 tree
      float t1 = fmaxf(fmaxf(v[3], v[4]), v[5]);
      float t2 = fmaxf(fmaxf(v[6], v[7]), v[8]);
      outp[l] = fmaxf(fmaxf(t0, t1), t2);  // coalesced
    }

    // 3. counted-vmcnt barrier: per-wave vmem issue order this round was
    //    [4x DMA(p+1)][4x store(p)]; in-order retire => vmcnt(4) means
    //    DMA(p+1) landed while stores stay in flight (T4). ds_reads were
    //    consumed by the fmax chain, so lgkm is already drained here.
    if (p + 1 < ROWS_PER_BLK) {
      asm volatile("s_waitcnt vmcnt(4)" ::: "memory");
      __builtin_amdgcn_s_barrier();
    }
    // last round: end-of-kernel implicit drain covers the stores
  }
#undef STAGE_ROW
}

// ---------------------------------------------------------------------------
// Fallback (ws too small): read raw indices + mask directly.
// ---------------------------------------------------------------------------
__global__ __launch_bounds__(256) void pool_kernel_direct(
    const float* __restrict__ img, const int* __restrict__ idx,
    const float* __restrict__ mask, float* __restrict__ out) {
  __shared__ __align__(16) float row[N_ + 4];
  const int bf = blockIdx.x;
  const int tid = threadIdx.x;

  const float4* src4 = (const float4*)(img + (size_t)bf * N_);
  float4* row4 = (float4*)row;
#pragma unroll
  for (int i = 0; i < 16; ++i) {
    int j = i * 256 + tid;
    row4[j] = src4[j];
  }
  __syncthreads();

  float* outp = out + (size_t)bf * L_;
  for (int it = 0; it < L_ / 256; ++it) {
    int l = it * 256 + tid;
    float m = -INFINITY;
#pragma unroll
    for (int k = 0; k < K_; ++k) {
      int t = l * K_ + k;
      float v = (mask[t] != 0.0f) ? row[idx[t]] : 0.0f;
      m = fmaxf(m, v);
    }
    outp[l] = m;
  }
}

extern "C" void kernel_launch(void* const* d_in, const int* in_sizes, int n_in,
                              void* d_out, int out_size, void* d_ws, size_t ws_size,
                              hipStream_t stream) {
  const float* img = (const float*)d_in[0];
  const int* idx = (const int*)d_in[1];
  const float* mask = (const float*)d_in[2];
  float* out = (float*)d_out;

  const size_t comb_bytes = (size_t)L_ * K_ * sizeof(unsigned short);
  if (ws_size >= comb_bytes) {
    unsigned short* comb = (unsigned short*)d_ws;
    int total = L_ * K_;
    prep_comb_kernel<<<(total + 255) / 256, 256, 0, stream>>>(idx, mask, comb);
    pool_pipe_kernel<<<NBLK, NTHR, 0, stream>>>(img, comb, out);
  } else {
    pool_kernel_direct<<<B_ * F_, 256, 0, stream>>>(img, idx, mask, out);
  }
}